// Round 9
// baseline (147.587 us; speedup 1.0000x reference)
//
#include <hip/hip_runtime.h>
#include <hip/hip_bf16.h>
#include <math.h>

// Problem constants: B=4, T=4096, C=1024, H=64
#define Bn 4
#define Tn 4096
#define Cn 1024
#define Hn 64

typedef __bf16 bf16_t;
typedef __bf16 bf16x8 __attribute__((ext_vector_type(8)));
typedef __bf16 bf16x4 __attribute__((ext_vector_type(4)));
typedef float f32x4 __attribute__((ext_vector_type(4)));

// bf16-element workspace offsets
#define WT_OFF 0
#define Q_OFF   196608
#define K_OFF   (Q_OFF + 1048576)
#define VT_OFF  (K_OFF + 1048576)
#define PART_OFF (VT_OFF + 1048576)     // 3,342,336: Opart bf16 region
// attn tiling: 128-row Q-tiles (32/batch), 64-col units, <=8 splits/tile
#define NTILE 32
#define NSMX 8
#define SLOTS (Bn * NTILE * NSMX)       // 1024 slots x 8192 el (16 KB bf16)

// ---------------------------------------------------------------------------
// Kernel 0: WT[n][k] = W_sel[k][n&63] bf16 (scale*log2e folded into Wq rows).
// ---------------------------------------------------------------------------
__global__ void wt_kernel(const float* __restrict__ Wq, const float* __restrict__ Wk,
                          const float* __restrict__ Wv, bf16_t* __restrict__ WT) {
    int idx = blockIdx.x * 256 + threadIdx.x;   // idx = n*1024 + k
    int n = idx >> 10;
    int k = idx & 1023;
    const float* W = (n < 64) ? Wq : (n < 128) ? Wk : Wv;
    float s = (n < 64) ? 0.1803368801111204f : 1.0f;   // H^-0.5 * log2(e)
    WT[idx] = (bf16_t)(W[(size_t)k * 64 + (n & 63)] * s);
}

// ---------------------------------------------------------------------------
// Kernel 1: QKV projection v8 — occupancy scaling continued.
// Ladder: 47.6 (scatter) -> 37 (dense reads) -> 31 (2 blocks/CU) -> 31
// (pipeline/DMA/setprio: null x3). The two real wins share one mechanism:
// memory parallelism per CU. v8 pushes it again: BN 96->64, grid 768 =
// 3 blocks/CU (LDS 32 KB, capacity 5; 3 waves/SIMD). The "N-sibling
// x re-fetch" counter-theory is refuted by rounds 0-3: FOUR N-tiles per
// x slice showed FETCH 34 MB << 4x67 MB (L2/L3 dedups). N-siblings
// (blk, blk+8, blk+16) pinned to one XCD: j2 = (blk>>3)%3,
// mg = ((blk>>3)/3)*8 + (blk&7) — bijective for grid 768.
// W staged via async global_load_lds (linear LDS dest, swizzle carried in
// the per-lane GLOBAL source chunk, rule #21); x staged via reg+cvt.
// ---------------------------------------------------------------------------
__launch_bounds__(256, 3)
__global__ void proj_kernel(const float* __restrict__ x, const bf16_t* __restrict__ WT,
                            bf16_t* __restrict__ q, bf16_t* __restrict__ kmat,
                            bf16_t* __restrict__ vt) {
    __shared__ bf16_t xtile[64][128];    // swizzled: chunk c at c^((row&3)<<2)
    __shared__ bf16_t wtile[64][128];    // LINEAR; swizzle in global src chunk

    const int tid  = threadIdx.x;
    const int wave = tid >> 6;
    const int lane = tid & 63;
    const int l15  = lane & 15;
    const int quad = lane >> 4;
    const int blk  = blockIdx.x;
    const int q3   = blk >> 3;                      // 0..95
    const int j2   = q3 % 3;                        // N-tile 0..2
    const int mg   = (q3 / 3) * 8 + (blk & 7);      // 0..255; siblings same mg+XCD
    const int n0   = j2 * 64;

    const int mrow = mg * 64;
    const int srow = tid >> 5;           // 0..7 (32-lane half -> dense 512B segment)
    const int sc   = tid & 31;           // float4 index within 512 B row chunk

    // W async staging: wave w covers rows w*16 .. w*16+16, one DMA per 4 rows
    // (64 lanes x 16 B = 4 rows x 16 chunks). LDS linear; global chunk carries
    // the involution: chunk = (lane&15) ^ ((lane>>4)<<2), row&3 == lane>>4.
    const int wrow_l = (lane >> 4);                          // 0..3
    const int wchunk = (lane & 15) ^ (wrow_l << 2);          // swizzled src chunk

    f32x4 acc[2][2];
#pragma unroll
    for (int nn = 0; nn < 2; ++nn)
#pragma unroll
        for (int rt = 0; rt < 2; ++rt)
            acc[nn][rt] = (f32x4){0.f, 0.f, 0.f, 0.f};

    const int rbase = (wave >> 1) * 32;  // A rows for this wave
    const int cbase = (wave & 1) * 32;   // B cols for this wave

    for (int kt = 0; kt < 8; ++kt) {
        const int k0 = kt * 128;
        // ---- x prefetch to regs: 8 independent dense float4 ----
        float4 xr[8];
        const float* xg = x + (size_t)(mrow + srow) * Cn + k0 + sc * 4;
#pragma unroll
        for (int rr = 0; rr < 8; ++rr)
            xr[rr] = *(const float4*)(xg + (size_t)rr * 8 * Cn);

        if (kt) __syncthreads();         // previous tile fully consumed

        // ---- W: async DMA global->LDS (4 x global_load_lds dwordx4) ----
#pragma unroll
        for (int i = 0; i < 4; ++i) {
            const int row = wave * 16 + i * 4 + wrow_l;
            const bf16_t* src = WT + (size_t)(n0 + row) * Cn + k0 + wchunk * 8;
            __builtin_amdgcn_global_load_lds(
                (const __attribute__((address_space(1))) void*)src,
                (__attribute__((address_space(3))) void*)&wtile[wave * 16 + i * 4][0],
                16, 0, 0);
        }

        // ---- x: cvt + swizzled LDS write ----
#pragma unroll
        for (int rr = 0; rr < 8; ++rr) {
            float4 v = xr[rr];
            bf16x4 c;
            c[0] = (bf16_t)v.x; c[1] = (bf16_t)v.y; c[2] = (bf16_t)v.z; c[3] = (bf16_t)v.w;
            int el = (((sc >> 1) ^ ((srow & 3) << 2)) << 3) + (sc & 1) * 4;
            *(bf16x4*)&xtile[srow + rr * 8][el] = c;
        }
        __syncthreads();                 // drains vmcnt (incl. DMA) + lgkm

        // ---- compute: 4 k-steps of 32 ----
#pragma unroll
        for (int ks = 0; ks < 4; ++ks) {
            const int u = (((ks << 2) | quad) ^ ((l15 & 3) << 2)) << 3;
            bf16x8 af[2];
#pragma unroll
            for (int rt = 0; rt < 2; ++rt)
                af[rt] = *(const bf16x8*)&xtile[rbase + rt * 16 + l15][u];
#pragma unroll
            for (int nn = 0; nn < 2; ++nn) {
                bf16x8 b = *(const bf16x8*)&wtile[cbase + nn * 16 + l15][u];
#pragma unroll
                for (int rt = 0; rt < 2; ++rt)
                    acc[nn][rt] = __builtin_amdgcn_mfma_f32_16x16x32_bf16(af[rt], b, acc[nn][rt], 0, 0, 0);
            }
        }
    }

    // ---- epilogue: C/D layout col=lane&15, row=quad*4+reg ----
#pragma unroll
    for (int nn = 0; nn < 2; ++nn) {
        int n = n0 + cbase + nn * 16 + l15;
#pragma unroll
        for (int rt = 0; rt < 2; ++rt) {
#pragma unroll
            for (int r = 0; r < 4; ++r) {
                int row = mrow + rbase + rt * 16 + quad * 4 + r;
                float v = acc[nn][rt][r];
                if (n < 64) {
                    q[(size_t)row * Hn + n] = (bf16_t)v;
                } else if (n < 128) {
                    kmat[(size_t)row * Hn + (n - 64)] = (bf16_t)v;
                } else {
                    int b  = row >> 12;
                    int tr = row & (Tn - 1);
                    vt[((size_t)b * Hn + (n - 128)) * Tn + tr] = (bf16_t)v;
                }
            }
        }
    }
}

// ---------------------------------------------------------------------------
// Kernel 2: split-KV causal flash attention, 512 thr (8 waves), 128-row
// Q-tile per block: K/V double-buffered staging (2x18 KB) feeds 8 waves,
// ONE barrier per 64-key unit. Tile t has 2t+2 units, ns=ceil(units/8)
// splits round-robin -> 576 blocks. 54 KB LDS. Coalesced bf16 partials.
// s_setprio around MFMA clusters (measured ~null here; kept, harmless).
// ---------------------------------------------------------------------------
__launch_bounds__(512, 4)
__global__ void attn_part(const bf16_t* __restrict__ q, const bf16_t* __restrict__ kmat,
                          const bf16_t* __restrict__ vt, bf16_t* __restrict__ Opart,
                          float* __restrict__ lpart) {
    __shared__ bf16_t kbuf[2][64][72];
    __shared__ bf16_t vbuf[2][64][72];
    __shared__ bf16_t p_lds[8][16][72];

    const int tid  = threadIdx.x;
    const int wave = tid >> 6;
    const int lane = tid & 63;
    const int l15  = lane & 15;
    const int quad = lane >> 4;

    // ---- decode (b, tile t, split s): cum(g) = 2g(g+1), 4 tiles/group ----
    const int blk = blockIdx.x;
    const int b   = blk & 3;
    const int w   = blk >> 2;           // 0..143
    int g = (int)((sqrtf(1.0f + 2.0f * (float)w) - 1.0f) * 0.5f);
    while (2 * (g + 1) * (g + 2) <= w) ++g;
    while (2 * g * (g + 1) > w) --g;
    const int rem = w - 2 * g * (g + 1);    // 0 .. 4(g+1)-1
    const int ns  = g + 1;
    const int t   = 4 * g + rem / ns;       // q-tile 0..31 (128 rows)
    const int s   = rem - (rem / ns) * ns;  // split 0..ns-1
    const int n_u = 2 * t + 2;              // KV units for this tile
    const int cnt = (n_u - 1 - s) / ns + 1; // units for this split
    const int q0  = t * 128;

    size_t qbase = ((size_t)b * Tn + q0 + wave * 16 + l15) * Hn;
    bf16x8 qf0 = *(const bf16x8*)(q + qbase + quad * 8);
    bf16x8 qf1 = *(const bf16x8*)(q + qbase + 32 + quad * 8);

    const bf16_t* kb = kmat + (size_t)b * Tn * Hn;
    const bf16_t* vb = vt + (size_t)b * Hn * Tn;

    f32x4 acc_o[4];
#pragma unroll
    for (int i = 0; i < 4; ++i) acc_o[i] = (f32x4){0.f, 0.f, 0.f, 0.f};
    float lsum[4] = {0.f, 0.f, 0.f, 0.f};

    const int srow = tid >> 3;   // staging: 64 rows x 8 chunks over 512 thr
    const int sc8  = tid & 7;

    uint4 kr, vr;
#define LOAD_UNIT(uu)                                                           \
    {                                                                           \
        const int s0l = (uu) * 64;                                              \
        kr = *(const uint4*)(kb + (size_t)(s0l + srow) * Hn + sc8 * 8);         \
        vr = *(const uint4*)(vb + (size_t)srow * Tn + s0l + sc8 * 8);           \
    }

    LOAD_UNIT(s);
    int u = s;
    int cur = 0;
    *(uint4*)&kbuf[0][srow][sc8 * 8] = kr;
    *(uint4*)&vbuf[0][srow][sc8 * 8] = vr;

    for (int i = 0; i < cnt; ++i) {
        __syncthreads();                    // buf[cur] visible; buf[cur^1] free
        const int un = u + ns;
        if (i + 1 < cnt) LOAD_UNIT(un);     // in flight across compute

        // ---- S = Q K^T (scale pre-folded into q) ----
        f32x4 accs[4];
#pragma unroll
        for (int ts = 0; ts < 4; ++ts) accs[ts] = (f32x4){0.f, 0.f, 0.f, 0.f};
        __builtin_amdgcn_s_setprio(1);
#pragma unroll
        for (int ts = 0; ts < 4; ++ts) {
            bf16x8 kf0 = *(const bf16x8*)&kbuf[cur][ts * 16 + l15][quad * 8];
            bf16x8 kf1 = *(const bf16x8*)&kbuf[cur][ts * 16 + l15][32 + quad * 8];
            accs[ts] = __builtin_amdgcn_mfma_f32_16x16x32_bf16(qf0, kf0, accs[ts], 0, 0, 0);
            accs[ts] = __builtin_amdgcn_mfma_f32_16x16x32_bf16(qf1, kf1, accs[ts], 0, 0, 0);
        }
        __builtin_amdgcn_s_setprio(0);
        // ---- causal mask: only when unit overlaps/exceeds wave's rows ----
        const int s0 = u * 64;
        const int rowb = q0 + wave * 16 + quad * 4;
        if (s0 + 63 > q0 + wave * 16) {        // wave-uniform
#pragma unroll
            for (int ts = 0; ts < 4; ++ts) {
                int col = s0 + ts * 16 + l15;
#pragma unroll
                for (int r = 0; r < 4; ++r)
                    accs[ts][r] = (col > rowb + r) ? -128.f : accs[ts][r];
            }
        }
        // ---- P = exp2(S); per-lane l; P -> wave-private LDS (C->A) ----
#pragma unroll
        for (int ts = 0; ts < 4; ++ts) {
#pragma unroll
            for (int r = 0; r < 4; ++r) {
                float p = exp2f(accs[ts][r]);
                lsum[r] += p;
                p_lds[wave][quad * 4 + r][ts * 16 + l15] = (bf16_t)p;
            }
        }
        // ---- O += P V ----
        __builtin_amdgcn_s_setprio(1);
#pragma unroll
        for (int kk = 0; kk < 64; kk += 32) {
            bf16x8 pf = *(const bf16x8*)&p_lds[wave][l15][kk + quad * 8];
#pragma unroll
            for (int t2 = 0; t2 < 4; ++t2) {
                bf16x8 vf = *(const bf16x8*)&vbuf[cur][t2 * 16 + l15][kk + quad * 8];
                acc_o[t2] = __builtin_amdgcn_mfma_f32_16x16x32_bf16(pf, vf, acc_o[t2], 0, 0, 0);
            }
        }
        __builtin_amdgcn_s_setprio(0);
        // ---- stage next unit into the buffer everyone is done reading ----
        if (i + 1 < cnt) {
            *(uint4*)&kbuf[cur ^ 1][srow][sc8 * 8] = kr;
            *(uint4*)&vbuf[cur ^ 1][srow][sc8 * 8] = vr;
        }
        u = un;
        cur ^= 1;
    }
#undef LOAD_UNIT

    // ---- one deferred cross-lane l reduction ----
#pragma unroll
    for (int r = 0; r < 4; ++r) {
        float v = lsum[r];
        v += __shfl_xor(v, 1);
        v += __shfl_xor(v, 2);
        v += __shfl_xor(v, 4);
        v += __shfl_xor(v, 8);
        lsum[r] = v;
    }
    // ---- coalesced partials: [slot][tid][16] bf16, register order ----
    const int slot = (b * NTILE + t) * NSMX + s;
    bf16x8 o0, o1;
#pragma unroll
    for (int e = 0; e < 8; ++e) { o0[e] = (bf16_t)acc_o[e >> 2][e & 3]; o1[e] = (bf16_t)acc_o[2 + (e >> 2)][e & 3]; }
    bf16_t* op = Opart + (size_t)slot * 8192 + (size_t)tid * 16;
    *(bf16x8*)op = o0;
    *(bf16x8*)(op + 8) = o1;
    if (l15 == 0) {
#pragma unroll
        for (int r = 0; r < 4; ++r)
            lpart[(size_t)slot * 128 + wave * 16 + quad * 4 + r] = lsum[r];
    }
}

// ---------------------------------------------------------------------------
// Kernel 3: combine partials + normalize. Grid (32, B), 512 thr mirroring
// attn lane structure: thread sums its own 16 contiguous elements per slot.
// ---------------------------------------------------------------------------
__launch_bounds__(512)
__global__ void combine_kernel(const bf16_t* __restrict__ Opart, const float* __restrict__ lpart,
                               float* __restrict__ out) {
    const int t = blockIdx.x;
    const int b = blockIdx.y;
    const int ns = (t >> 2) + 1;
    const int tid  = threadIdx.x;
    const int wave = tid >> 6;
    const int lane = tid & 63;
    const int l15  = lane & 15;
    const int quad = lane >> 4;

    float o[16];
#pragma unroll
    for (int i = 0; i < 16; ++i) o[i] = 0.f;
    float L[4] = {0.f, 0.f, 0.f, 0.f};

    for (int s = 0; s < ns; ++s) {
        const int slot = (b * NTILE + t) * NSMX + s;
        const bf16_t* op = Opart + (size_t)slot * 8192 + (size_t)tid * 16;
        bf16x8 v0 = *(const bf16x8*)op;
        bf16x8 v1 = *(const bf16x8*)(op + 8);
#pragma unroll
        for (int i = 0; i < 8; ++i) { o[i] += (float)v0[i]; o[8 + i] += (float)v1[i]; }
#pragma unroll
        for (int r = 0; r < 4; ++r)
            L[r] += lpart[(size_t)slot * 128 + wave * 16 + quad * 4 + r];
    }
    float inv[4];
#pragma unroll
    for (int r = 0; r < 4; ++r) inv[r] = 1.f / L[r];
    // o[e] with e = t2*4+r -> row = t*128+wave*16+quad*4+r, col = t2*16+l15
#pragma unroll
    for (int t2 = 0; t2 < 4; ++t2) {
#pragma unroll
        for (int r = 0; r < 4; ++r) {
            size_t row = (size_t)b * Tn + t * 128 + wave * 16 + quad * 4 + r;
            out[row * Hn + t2 * 16 + l15] = o[t2 * 4 + r] * inv[r];
        }
    }
}

// ---------------------------------------------------------------------------
extern "C" void kernel_launch(void* const* d_in, const int* in_sizes, int n_in,
                              void* d_out, int out_size, void* d_ws, size_t ws_size,
                              hipStream_t stream) {
    const float* x  = (const float*)d_in[0];
    const float* Wq = (const float*)d_in[1];
    const float* Wk = (const float*)d_in[2];
    const float* Wv = (const float*)d_in[3];
    float* out = (float*)d_out;

    bf16_t* wsb = (bf16_t*)d_ws;
    bf16_t* WT = wsb + WT_OFF;
    bf16_t* qb = wsb + Q_OFF;
    bf16_t* kb = wsb + K_OFF;
    bf16_t* vt = wsb + VT_OFF;
    bf16_t* Opart = wsb + PART_OFF;
    float*  lpart = (float*)(Opart + (size_t)SLOTS * 8192);

    // blocks/batch = sum_t (t/4+1) = 144
    const int per_batch = 144;

    wt_kernel<<<dim3(192 * 1024 / 256), dim3(256), 0, stream>>>(Wq, Wk, Wv, WT);
    proj_kernel<<<dim3(768), dim3(256), 0, stream>>>(x, WT, qb, kb, vt);
    attn_part<<<dim3(per_batch * Bn), dim3(512), 0, stream>>>(qb, kb, vt, Opart, lpart);
    combine_kernel<<<dim3(NTILE, Bn), dim3(512), 0, stream>>>(Opart, lpart, out);
}

// Round 10
// 145.601 us; speedup vs baseline: 1.0136x; 1.0136x over previous
//
#include <hip/hip_runtime.h>
#include <hip/hip_bf16.h>
#include <math.h>

// Problem constants: B=4, T=4096, C=1024, H=64
#define Bn 4
#define Tn 4096
#define Cn 1024
#define Hn 64

typedef __bf16 bf16_t;
typedef __bf16 bf16x8 __attribute__((ext_vector_type(8)));
typedef __bf16 bf16x4 __attribute__((ext_vector_type(4)));
typedef float f32x4 __attribute__((ext_vector_type(4)));

// bf16-element workspace offsets
#define WT_OFF 0
#define Q_OFF   196608
#define K_OFF   (Q_OFF + 1048576)
#define VT_OFF  (K_OFF + 1048576)
#define PART_OFF (VT_OFF + 1048576)     // 3,342,336: Opart bf16 region
// attn tiling: 128-row Q-tiles (32/batch), 64-col units, <=8 splits/tile
#define NTILE 32
#define NSMX 8
#define SLOTS (Bn * NTILE * NSMX)       // 1024 slots x 8192 el (16 KB bf16)

// ---------------------------------------------------------------------------
// Kernel 0: WT[n][k] = W_sel[k][n&63] bf16 (scale*log2e folded into Wq rows).
// ---------------------------------------------------------------------------
__global__ void wt_kernel(const float* __restrict__ Wq, const float* __restrict__ Wk,
                          const float* __restrict__ Wv, bf16_t* __restrict__ WT) {
    int idx = blockIdx.x * 256 + threadIdx.x;   // idx = n*1024 + k
    int n = idx >> 10;
    int k = idx & 1023;
    const float* W = (n < 64) ? Wq : (n < 128) ? Wk : Wv;
    float s = (n < 64) ? 0.1803368801111204f : 1.0f;   // H^-0.5 * log2(e)
    WT[idx] = (bf16_t)(W[(size_t)k * 64 + (n & 63)] * s);
}

// ---------------------------------------------------------------------------
// Kernel 1: QKV projection v9 — phase-count halving (BK=256).
// Ladder: 47.6 (scatter) -> 37 (dense) -> 31 (2 blocks/CU); occupancy 3/CU
// REGRESSED (r9: +3.4); all scheduling-shape changes null (r6/r7/r8).
// Model: each {load->stage->barrier->compute} phase carries a large fixed
// cost (~3.9 us/phase at 8 phases) invariant to internal schedule. Test:
// halve phases. BK=256 -> 4 K-tiles; per phase 2x work (16 x-float4 + 12
// W-DMA + 8 ks), LDS 80 KB (2-half xtile 32 KB + wtile 48 KB) -> keeps
// the proven 2 blocks/CU plateau. BN=96, grid 512 (r8 base = 144.17 us).
// W staged via async global_load_lds (linear LDS dest, swizzle in the
// per-lane GLOBAL source chunk, rule #21); x staged via reg+cvt.
// ---------------------------------------------------------------------------
__launch_bounds__(256, 2)
__global__ void proj_kernel(const float* __restrict__ x, const bf16_t* __restrict__ WT,
                            bf16_t* __restrict__ q, bf16_t* __restrict__ kmat,
                            bf16_t* __restrict__ vt) {
    __shared__ bf16_t xtile[2][64][128];  // [K-half][row][el]; swz chunk^((row&3)<<2)
    __shared__ bf16_t wtile[2][96][128];  // LINEAR; swizzle in global src chunk

    const int tid  = threadIdx.x;
    const int wave = tid >> 6;
    const int lane = tid & 63;
    const int l15  = lane & 15;
    const int quad = lane >> 4;
    const int blk  = blockIdx.x;
    const int mg = ((blk >> 4) << 3) | (blk & 7);   // 0..255; blk,blk+8 same mg+XCD
    const int j2 = (blk >> 3) & 1;                  // N-tile 0..1
    const int n0 = j2 * 96;

    const int mrow = mg * 64;
    const int srow = tid >> 5;           // 0..7 (32-lane half -> dense 512B segment)
    const int sc   = tid & 31;           // float4 index within 512 B row chunk

    // W async staging: wave w covers rows w*24 .. w*24+24 per half, one DMA
    // per 4 rows. LDS linear; global chunk carries the involution:
    // chunk = (lane&15) ^ ((lane>>4)<<2), row&3 == lane>>4.
    const int wrow_l = (lane >> 4);                          // 0..3
    const int wchunk = (lane & 15) ^ (wrow_l << 2);          // swizzled src chunk

    f32x4 acc[3][2];
#pragma unroll
    for (int nn = 0; nn < 3; ++nn)
#pragma unroll
        for (int rt = 0; rt < 2; ++rt)
            acc[nn][rt] = (f32x4){0.f, 0.f, 0.f, 0.f};

    const int rbase = (wave >> 1) * 32;  // A rows for this wave
    const int cbase = (wave & 1) * 48;   // B cols for this wave

    for (int kt = 0; kt < 4; ++kt) {
        const int k0 = kt * 256;
        // ---- x prefetch to regs: 16 independent dense float4 (2 halves) ----
        float4 xr[2][8];
#pragma unroll
        for (int h = 0; h < 2; ++h) {
            const float* xg = x + (size_t)(mrow + srow) * Cn + k0 + h * 128 + sc * 4;
#pragma unroll
            for (int rr = 0; rr < 8; ++rr)
                xr[h][rr] = *(const float4*)(xg + (size_t)rr * 8 * Cn);
        }

        if (kt) __syncthreads();         // previous tile fully consumed

        // ---- W: async DMA global->LDS (12 x global_load_lds dwordx4) ----
#pragma unroll
        for (int h = 0; h < 2; ++h) {
#pragma unroll
            for (int i = 0; i < 6; ++i) {
                const int row = wave * 24 + i * 4 + wrow_l;
                const bf16_t* src = WT + (size_t)(n0 + row) * Cn + k0 + h * 128 + wchunk * 8;
                __builtin_amdgcn_global_load_lds(
                    (const __attribute__((address_space(1))) void*)src,
                    (__attribute__((address_space(3))) void*)&wtile[h][wave * 24 + i * 4][0],
                    16, 0, 0);
            }
        }

        // ---- x: cvt + swizzled LDS write ----
#pragma unroll
        for (int h = 0; h < 2; ++h) {
#pragma unroll
            for (int rr = 0; rr < 8; ++rr) {
                float4 v = xr[h][rr];
                bf16x4 c;
                c[0] = (bf16_t)v.x; c[1] = (bf16_t)v.y; c[2] = (bf16_t)v.z; c[3] = (bf16_t)v.w;
                int el = (((sc >> 1) ^ ((srow & 3) << 2)) << 3) + (sc & 1) * 4;
                *(bf16x4*)&xtile[h][srow + rr * 8][el] = c;
            }
        }
        __syncthreads();                 // drains vmcnt (incl. DMA) + lgkm

        // ---- compute: 8 k-steps of 32 (two halves) ----
#pragma unroll
        for (int ks = 0; ks < 8; ++ks) {
            const int h  = ks >> 2;
            const int u  = ((((ks & 3) << 2) | quad) ^ ((l15 & 3) << 2)) << 3;
            bf16x8 af[2];
#pragma unroll
            for (int rt = 0; rt < 2; ++rt)
                af[rt] = *(const bf16x8*)&xtile[h][rbase + rt * 16 + l15][u];
#pragma unroll
            for (int nn = 0; nn < 3; ++nn) {
                bf16x8 b = *(const bf16x8*)&wtile[h][cbase + nn * 16 + l15][u];
#pragma unroll
                for (int rt = 0; rt < 2; ++rt)
                    acc[nn][rt] = __builtin_amdgcn_mfma_f32_16x16x32_bf16(af[rt], b, acc[nn][rt], 0, 0, 0);
            }
        }
    }

    // ---- epilogue: C/D layout col=lane&15, row=quad*4+reg ----
#pragma unroll
    for (int nn = 0; nn < 3; ++nn) {
        int n = n0 + cbase + nn * 16 + l15;
#pragma unroll
        for (int rt = 0; rt < 2; ++rt) {
#pragma unroll
            for (int r = 0; r < 4; ++r) {
                int row = mrow + rbase + rt * 16 + quad * 4 + r;
                float v = acc[nn][rt][r];
                if (n < 64) {
                    q[(size_t)row * Hn + n] = (bf16_t)v;
                } else if (n < 128) {
                    kmat[(size_t)row * Hn + (n - 64)] = (bf16_t)v;
                } else {
                    int b  = row >> 12;
                    int tr = row & (Tn - 1);
                    vt[((size_t)b * Hn + (n - 128)) * Tn + tr] = (bf16_t)v;
                }
            }
        }
    }
}

// ---------------------------------------------------------------------------
// Kernel 2: split-KV causal flash attention, 512 thr (8 waves), 128-row
// Q-tile per block: K/V double-buffered staging (2x18 KB) feeds 8 waves,
// ONE barrier per 64-key unit. Tile t has 2t+2 units, ns=ceil(units/8)
// splits round-robin -> 576 blocks. 54 KB LDS. Coalesced bf16 partials.
// s_setprio around MFMA clusters (measured ~null here; kept, harmless).
// ---------------------------------------------------------------------------
__launch_bounds__(512, 4)
__global__ void attn_part(const bf16_t* __restrict__ q, const bf16_t* __restrict__ kmat,
                          const bf16_t* __restrict__ vt, bf16_t* __restrict__ Opart,
                          float* __restrict__ lpart) {
    __shared__ bf16_t kbuf[2][64][72];
    __shared__ bf16_t vbuf[2][64][72];
    __shared__ bf16_t p_lds[8][16][72];

    const int tid  = threadIdx.x;
    const int wave = tid >> 6;
    const int lane = tid & 63;
    const int l15  = lane & 15;
    const int quad = lane >> 4;

    // ---- decode (b, tile t, split s): cum(g) = 2g(g+1), 4 tiles/group ----
    const int blk = blockIdx.x;
    const int b   = blk & 3;
    const int w   = blk >> 2;           // 0..143
    int g = (int)((sqrtf(1.0f + 2.0f * (float)w) - 1.0f) * 0.5f);
    while (2 * (g + 1) * (g + 2) <= w) ++g;
    while (2 * g * (g + 1) > w) --g;
    const int rem = w - 2 * g * (g + 1);    // 0 .. 4(g+1)-1
    const int ns  = g + 1;
    const int t   = 4 * g + rem / ns;       // q-tile 0..31 (128 rows)
    const int s   = rem - (rem / ns) * ns;  // split 0..ns-1
    const int n_u = 2 * t + 2;              // KV units for this tile
    const int cnt = (n_u - 1 - s) / ns + 1; // units for this split
    const int q0  = t * 128;

    size_t qbase = ((size_t)b * Tn + q0 + wave * 16 + l15) * Hn;
    bf16x8 qf0 = *(const bf16x8*)(q + qbase + quad * 8);
    bf16x8 qf1 = *(const bf16x8*)(q + qbase + 32 + quad * 8);

    const bf16_t* kb = kmat + (size_t)b * Tn * Hn;
    const bf16_t* vb = vt + (size_t)b * Hn * Tn;

    f32x4 acc_o[4];
#pragma unroll
    for (int i = 0; i < 4; ++i) acc_o[i] = (f32x4){0.f, 0.f, 0.f, 0.f};
    float lsum[4] = {0.f, 0.f, 0.f, 0.f};

    const int srow = tid >> 3;   // staging: 64 rows x 8 chunks over 512 thr
    const int sc8  = tid & 7;

    uint4 kr, vr;
#define LOAD_UNIT(uu)                                                           \
    {                                                                           \
        const int s0l = (uu) * 64;                                              \
        kr = *(const uint4*)(kb + (size_t)(s0l + srow) * Hn + sc8 * 8);         \
        vr = *(const uint4*)(vb + (size_t)srow * Tn + s0l + sc8 * 8);           \
    }

    LOAD_UNIT(s);
    int u = s;
    int cur = 0;
    *(uint4*)&kbuf[0][srow][sc8 * 8] = kr;
    *(uint4*)&vbuf[0][srow][sc8 * 8] = vr;

    for (int i = 0; i < cnt; ++i) {
        __syncthreads();                    // buf[cur] visible; buf[cur^1] free
        const int un = u + ns;
        if (i + 1 < cnt) LOAD_UNIT(un);     // in flight across compute

        // ---- S = Q K^T (scale pre-folded into q) ----
        f32x4 accs[4];
#pragma unroll
        for (int ts = 0; ts < 4; ++ts) accs[ts] = (f32x4){0.f, 0.f, 0.f, 0.f};
        __builtin_amdgcn_s_setprio(1);
#pragma unroll
        for (int ts = 0; ts < 4; ++ts) {
            bf16x8 kf0 = *(const bf16x8*)&kbuf[cur][ts * 16 + l15][quad * 8];
            bf16x8 kf1 = *(const bf16x8*)&kbuf[cur][ts * 16 + l15][32 + quad * 8];
            accs[ts] = __builtin_amdgcn_mfma_f32_16x16x32_bf16(qf0, kf0, accs[ts], 0, 0, 0);
            accs[ts] = __builtin_amdgcn_mfma_f32_16x16x32_bf16(qf1, kf1, accs[ts], 0, 0, 0);
        }
        __builtin_amdgcn_s_setprio(0);
        // ---- causal mask: only when unit overlaps/exceeds wave's rows ----
        const int s0 = u * 64;
        const int rowb = q0 + wave * 16 + quad * 4;
        if (s0 + 63 > q0 + wave * 16) {        // wave-uniform
#pragma unroll
            for (int ts = 0; ts < 4; ++ts) {
                int col = s0 + ts * 16 + l15;
#pragma unroll
                for (int r = 0; r < 4; ++r)
                    accs[ts][r] = (col > rowb + r) ? -128.f : accs[ts][r];
            }
        }
        // ---- P = exp2(S); per-lane l; P -> wave-private LDS (C->A) ----
#pragma unroll
        for (int ts = 0; ts < 4; ++ts) {
#pragma unroll
            for (int r = 0; r < 4; ++r) {
                float p = exp2f(accs[ts][r]);
                lsum[r] += p;
                p_lds[wave][quad * 4 + r][ts * 16 + l15] = (bf16_t)p;
            }
        }
        // ---- O += P V ----
        __builtin_amdgcn_s_setprio(1);
#pragma unroll
        for (int kk = 0; kk < 64; kk += 32) {
            bf16x8 pf = *(const bf16x8*)&p_lds[wave][l15][kk + quad * 8];
#pragma unroll
            for (int t2 = 0; t2 < 4; ++t2) {
                bf16x8 vf = *(const bf16x8*)&vbuf[cur][t2 * 16 + l15][kk + quad * 8];
                acc_o[t2] = __builtin_amdgcn_mfma_f32_16x16x32_bf16(pf, vf, acc_o[t2], 0, 0, 0);
            }
        }
        __builtin_amdgcn_s_setprio(0);
        // ---- stage next unit into the buffer everyone is done reading ----
        if (i + 1 < cnt) {
            *(uint4*)&kbuf[cur ^ 1][srow][sc8 * 8] = kr;
            *(uint4*)&vbuf[cur ^ 1][srow][sc8 * 8] = vr;
        }
        u = un;
        cur ^= 1;
    }
#undef LOAD_UNIT

    // ---- one deferred cross-lane l reduction ----
#pragma unroll
    for (int r = 0; r < 4; ++r) {
        float v = lsum[r];
        v += __shfl_xor(v, 1);
        v += __shfl_xor(v, 2);
        v += __shfl_xor(v, 4);
        v += __shfl_xor(v, 8);
        lsum[r] = v;
    }
    // ---- coalesced partials: [slot][tid][16] bf16, register order ----
    const int slot = (b * NTILE + t) * NSMX + s;
    bf16x8 o0, o1;
#pragma unroll
    for (int e = 0; e < 8; ++e) { o0[e] = (bf16_t)acc_o[e >> 2][e & 3]; o1[e] = (bf16_t)acc_o[2 + (e >> 2)][e & 3]; }
    bf16_t* op = Opart + (size_t)slot * 8192 + (size_t)tid * 16;
    *(bf16x8*)op = o0;
    *(bf16x8*)(op + 8) = o1;
    if (l15 == 0) {
#pragma unroll
        for (int r = 0; r < 4; ++r)
            lpart[(size_t)slot * 128 + wave * 16 + quad * 4 + r] = lsum[r];
    }
}

// ---------------------------------------------------------------------------
// Kernel 3: combine partials + normalize. Grid (32, B), 512 thr mirroring
// attn lane structure: thread sums its own 16 contiguous elements per slot.
// ---------------------------------------------------------------------------
__launch_bounds__(512)
__global__ void combine_kernel(const bf16_t* __restrict__ Opart, const float* __restrict__ lpart,
                               float* __restrict__ out) {
    const int t = blockIdx.x;
    const int b = blockIdx.y;
    const int ns = (t >> 2) + 1;
    const int tid  = threadIdx.x;
    const int wave = tid >> 6;
    const int lane = tid & 63;
    const int l15  = lane & 15;
    const int quad = lane >> 4;

    float o[16];
#pragma unroll
    for (int i = 0; i < 16; ++i) o[i] = 0.f;
    float L[4] = {0.f, 0.f, 0.f, 0.f};

    for (int s = 0; s < ns; ++s) {
        const int slot = (b * NTILE + t) * NSMX + s;
        const bf16_t* op = Opart + (size_t)slot * 8192 + (size_t)tid * 16;
        bf16x8 v0 = *(const bf16x8*)op;
        bf16x8 v1 = *(const bf16x8*)(op + 8);
#pragma unroll
        for (int i = 0; i < 8; ++i) { o[i] += (float)v0[i]; o[8 + i] += (float)v1[i]; }
#pragma unroll
        for (int r = 0; r < 4; ++r)
            L[r] += lpart[(size_t)slot * 128 + wave * 16 + quad * 4 + r];
    }
    float inv[4];
#pragma unroll
    for (int r = 0; r < 4; ++r) inv[r] = 1.f / L[r];
    // o[e] with e = t2*4+r -> row = t*128+wave*16+quad*4+r, col = t2*16+l15
#pragma unroll
    for (int t2 = 0; t2 < 4; ++t2) {
#pragma unroll
        for (int r = 0; r < 4; ++r) {
            size_t row = (size_t)b * Tn + t * 128 + wave * 16 + quad * 4 + r;
            out[row * Hn + t2 * 16 + l15] = o[t2 * 4 + r] * inv[r];
        }
    }
}

// ---------------------------------------------------------------------------
extern "C" void kernel_launch(void* const* d_in, const int* in_sizes, int n_in,
                              void* d_out, int out_size, void* d_ws, size_t ws_size,
                              hipStream_t stream) {
    const float* x  = (const float*)d_in[0];
    const float* Wq = (const float*)d_in[1];
    const float* Wk = (const float*)d_in[2];
    const float* Wv = (const float*)d_in[3];
    float* out = (float*)d_out;

    bf16_t* wsb = (bf16_t*)d_ws;
    bf16_t* WT = wsb + WT_OFF;
    bf16_t* qb = wsb + Q_OFF;
    bf16_t* kb = wsb + K_OFF;
    bf16_t* vt = wsb + VT_OFF;
    bf16_t* Opart = wsb + PART_OFF;
    float*  lpart = (float*)(Opart + (size_t)SLOTS * 8192);

    // blocks/batch = sum_t (t/4+1) = 144
    const int per_batch = 144;

    wt_kernel<<<dim3(192 * 1024 / 256), dim3(256), 0, stream>>>(Wq, Wk, Wv, WT);
    proj_kernel<<<dim3(512), dim3(256), 0, stream>>>(x, WT, qb, kb, vt);
    attn_part<<<dim3(per_batch * Bn), dim3(512), 0, stream>>>(qb, kb, vt, Opart, lpart);
    combine_kernel<<<dim3(NTILE, Bn), dim3(512), 0, stream>>>(Opart, lpart, out);
}

// Round 11
// 145.146 us; speedup vs baseline: 1.0168x; 1.0031x over previous
//
#include <hip/hip_runtime.h>
#include <hip/hip_bf16.h>
#include <math.h>

// Problem constants: B=4, T=4096, C=1024, H=64
#define Bn 4
#define Tn 4096
#define Cn 1024
#define Hn 64

typedef __bf16 bf16_t;
typedef __bf16 bf16x8 __attribute__((ext_vector_type(8)));
typedef __bf16 bf16x4 __attribute__((ext_vector_type(4)));
typedef float f32x4 __attribute__((ext_vector_type(4)));

// bf16-element workspace offsets
#define WT_OFF 0
#define Q_OFF   196608
#define K_OFF   (Q_OFF + 1048576)
#define VT_OFF  (K_OFF + 1048576)
#define PART_OFF (VT_OFF + 1048576)     // 3,342,336: Opart bf16 region
// attn tiling: 128-row Q-tiles (32/batch), 64-col units, <=8 splits/tile
#define NTILE 32
#define NSMX 8
#define SLOTS (Bn * NTILE * NSMX)       // 1024 slots x 8192 el (16 KB bf16)

// ---------------------------------------------------------------------------
// Kernel 0: WT[n][k] = W_sel[k][n&63] bf16 (scale*log2e folded into Wq rows).
// ---------------------------------------------------------------------------
__global__ void wt_kernel(const float* __restrict__ Wq, const float* __restrict__ Wk,
                          const float* __restrict__ Wv, bf16_t* __restrict__ WT) {
    int idx = blockIdx.x * 256 + threadIdx.x;   // idx = n*1024 + k
    int n = idx >> 10;
    int k = idx & 1023;
    const float* W = (n < 64) ? Wq : (n < 128) ? Wk : Wv;
    float s = (n < 64) ? 0.1803368801111204f : 1.0f;   // H^-0.5 * log2(e)
    WT[idx] = (bf16_t)(W[(size_t)k * 64 + (n & 63)] * s);
}

// ---------------------------------------------------------------------------
// Kernel 1: QKV projection — BEST MEASURED CONFIG (round-7, 144.17 us total).
// Ladder: 47.6 (scatter) -> 37 (dense reads) -> 31 (2 blocks/CU plateau).
// Falsified since: pipeline shape (x3), async-DMA delta, setprio, 3
// blocks/CU (regressed), BK=256 phase-halving (regressed). Reverted to the
// empirical optimum: BN=96, BK=128, grid 512 = 256 M-groups x 2 N-tiles
// (pair blk/blk+8 shares x slice on one XCD), 40 KB LDS, W staged via
// async global_load_lds (linear LDS dest; swizzle carried in the per-lane
// GLOBAL source chunk, rule #21), x staged reg+cvt with dense 512 B
// segments issued before the barrier.
// ---------------------------------------------------------------------------
__launch_bounds__(256, 3)
__global__ void proj_kernel(const float* __restrict__ x, const bf16_t* __restrict__ WT,
                            bf16_t* __restrict__ q, bf16_t* __restrict__ kmat,
                            bf16_t* __restrict__ vt) {
    __shared__ bf16_t xtile[64][128];    // swizzled: chunk c at c^((row&3)<<2)
    __shared__ bf16_t wtile[96][128];    // LINEAR; swizzle in global src chunk

    const int tid  = threadIdx.x;
    const int wave = tid >> 6;
    const int lane = tid & 63;
    const int l15  = lane & 15;
    const int quad = lane >> 4;
    const int blk  = blockIdx.x;
    const int mg = ((blk >> 4) << 3) | (blk & 7);   // 0..255; blk,blk+8 same mg+XCD
    const int j2 = (blk >> 3) & 1;                  // N-tile 0..1
    const int n0 = j2 * 96;

    const int mrow = mg * 64;
    const int srow = tid >> 5;           // 0..7 (32-lane half -> dense 512B segment)
    const int sc   = tid & 31;           // float4 index within 512 B row chunk

    const int wrow_l = (lane >> 4);                          // 0..3
    const int wchunk = (lane & 15) ^ (wrow_l << 2);          // swizzled src chunk

    f32x4 acc[3][2];
#pragma unroll
    for (int nn = 0; nn < 3; ++nn)
#pragma unroll
        for (int rt = 0; rt < 2; ++rt)
            acc[nn][rt] = (f32x4){0.f, 0.f, 0.f, 0.f};

    const int rbase = (wave >> 1) * 32;  // A rows for this wave
    const int cbase = (wave & 1) * 48;   // B cols for this wave

    for (int kt = 0; kt < 8; ++kt) {
        const int k0 = kt * 128;
        // ---- x prefetch to regs: 8 independent dense float4 ----
        float4 xr[8];
        const float* xg = x + (size_t)(mrow + srow) * Cn + k0 + sc * 4;
#pragma unroll
        for (int rr = 0; rr < 8; ++rr)
            xr[rr] = *(const float4*)(xg + (size_t)rr * 8 * Cn);

        if (kt) __syncthreads();         // previous tile fully consumed

        // ---- W: async DMA global->LDS (6 x global_load_lds dwordx4) ----
#pragma unroll
        for (int i = 0; i < 6; ++i) {
            const int row = wave * 24 + i * 4 + wrow_l;
            const bf16_t* src = WT + (size_t)(n0 + row) * Cn + k0 + wchunk * 8;
            __builtin_amdgcn_global_load_lds(
                (const __attribute__((address_space(1))) void*)src,
                (__attribute__((address_space(3))) void*)&wtile[wave * 24 + i * 4][0],
                16, 0, 0);
        }

        // ---- x: cvt + swizzled LDS write ----
#pragma unroll
        for (int rr = 0; rr < 8; ++rr) {
            float4 v = xr[rr];
            bf16x4 c;
            c[0] = (bf16_t)v.x; c[1] = (bf16_t)v.y; c[2] = (bf16_t)v.z; c[3] = (bf16_t)v.w;
            int el = (((sc >> 1) ^ ((srow & 3) << 2)) << 3) + (sc & 1) * 4;
            *(bf16x4*)&xtile[srow + rr * 8][el] = c;
        }
        __syncthreads();                 // drains vmcnt (incl. DMA) + lgkm

        // ---- compute: 4 k-steps of 32 ----
#pragma unroll
        for (int ks = 0; ks < 4; ++ks) {
            const int u = (((ks << 2) | quad) ^ ((l15 & 3) << 2)) << 3;
            bf16x8 af[2];
#pragma unroll
            for (int rt = 0; rt < 2; ++rt)
                af[rt] = *(const bf16x8*)&xtile[rbase + rt * 16 + l15][u];
#pragma unroll
            for (int nn = 0; nn < 3; ++nn) {
                bf16x8 b = *(const bf16x8*)&wtile[cbase + nn * 16 + l15][u];
#pragma unroll
                for (int rt = 0; rt < 2; ++rt)
                    acc[nn][rt] = __builtin_amdgcn_mfma_f32_16x16x32_bf16(af[rt], b, acc[nn][rt], 0, 0, 0);
            }
        }
    }

    // ---- epilogue: C/D layout col=lane&15, row=quad*4+reg ----
#pragma unroll
    for (int nn = 0; nn < 3; ++nn) {
        int n = n0 + cbase + nn * 16 + l15;
#pragma unroll
        for (int rt = 0; rt < 2; ++rt) {
#pragma unroll
            for (int r = 0; r < 4; ++r) {
                int row = mrow + rbase + rt * 16 + quad * 4 + r;
                float v = acc[nn][rt][r];
                if (n < 64) {
                    q[(size_t)row * Hn + n] = (bf16_t)v;
                } else if (n < 128) {
                    kmat[(size_t)row * Hn + (n - 64)] = (bf16_t)v;
                } else {
                    int b  = row >> 12;
                    int tr = row & (Tn - 1);
                    vt[((size_t)b * Hn + (n - 128)) * Tn + tr] = (bf16_t)v;
                }
            }
        }
    }
}

// ---------------------------------------------------------------------------
// Kernel 2: split-KV causal flash attention, 512 thr (8 waves), 128-row
// Q-tile per block: K/V double-buffered staging (2x18 KB) feeds 8 waves,
// ONE barrier per 64-key unit. Tile t has 2t+2 units, ns=ceil(units/8)
// splits round-robin -> 576 blocks. 54 KB LDS. Coalesced bf16 partials.
// s_setprio around MFMA clusters (measured ~null here; kept, harmless).
// ---------------------------------------------------------------------------
__launch_bounds__(512, 4)
__global__ void attn_part(const bf16_t* __restrict__ q, const bf16_t* __restrict__ kmat,
                          const bf16_t* __restrict__ vt, bf16_t* __restrict__ Opart,
                          float* __restrict__ lpart) {
    __shared__ bf16_t kbuf[2][64][72];
    __shared__ bf16_t vbuf[2][64][72];
    __shared__ bf16_t p_lds[8][16][72];

    const int tid  = threadIdx.x;
    const int wave = tid >> 6;
    const int lane = tid & 63;
    const int l15  = lane & 15;
    const int quad = lane >> 4;

    // ---- decode (b, tile t, split s): cum(g) = 2g(g+1), 4 tiles/group ----
    const int blk = blockIdx.x;
    const int b   = blk & 3;
    const int w   = blk >> 2;           // 0..143
    int g = (int)((sqrtf(1.0f + 2.0f * (float)w) - 1.0f) * 0.5f);
    while (2 * (g + 1) * (g + 2) <= w) ++g;
    while (2 * g * (g + 1) > w) --g;
    const int rem = w - 2 * g * (g + 1);    // 0 .. 4(g+1)-1
    const int ns  = g + 1;
    const int t   = 4 * g + rem / ns;       // q-tile 0..31 (128 rows)
    const int s   = rem - (rem / ns) * ns;  // split 0..ns-1
    const int n_u = 2 * t + 2;              // KV units for this tile
    const int cnt = (n_u - 1 - s) / ns + 1; // units for this split
    const int q0  = t * 128;

    size_t qbase = ((size_t)b * Tn + q0 + wave * 16 + l15) * Hn;
    bf16x8 qf0 = *(const bf16x8*)(q + qbase + quad * 8);
    bf16x8 qf1 = *(const bf16x8*)(q + qbase + 32 + quad * 8);

    const bf16_t* kb = kmat + (size_t)b * Tn * Hn;
    const bf16_t* vb = vt + (size_t)b * Hn * Tn;

    f32x4 acc_o[4];
#pragma unroll
    for (int i = 0; i < 4; ++i) acc_o[i] = (f32x4){0.f, 0.f, 0.f, 0.f};
    float lsum[4] = {0.f, 0.f, 0.f, 0.f};

    const int srow = tid >> 3;   // staging: 64 rows x 8 chunks over 512 thr
    const int sc8  = tid & 7;

    uint4 kr, vr;
#define LOAD_UNIT(uu)                                                           \
    {                                                                           \
        const int s0l = (uu) * 64;                                              \
        kr = *(const uint4*)(kb + (size_t)(s0l + srow) * Hn + sc8 * 8);         \
        vr = *(const uint4*)(vb + (size_t)srow * Tn + s0l + sc8 * 8);           \
    }

    LOAD_UNIT(s);
    int u = s;
    int cur = 0;
    *(uint4*)&kbuf[0][srow][sc8 * 8] = kr;
    *(uint4*)&vbuf[0][srow][sc8 * 8] = vr;

    for (int i = 0; i < cnt; ++i) {
        __syncthreads();                    // buf[cur] visible; buf[cur^1] free
        const int un = u + ns;
        if (i + 1 < cnt) LOAD_UNIT(un);     // in flight across compute

        // ---- S = Q K^T (scale pre-folded into q) ----
        f32x4 accs[4];
#pragma unroll
        for (int ts = 0; ts < 4; ++ts) accs[ts] = (f32x4){0.f, 0.f, 0.f, 0.f};
        __builtin_amdgcn_s_setprio(1);
#pragma unroll
        for (int ts = 0; ts < 4; ++ts) {
            bf16x8 kf0 = *(const bf16x8*)&kbuf[cur][ts * 16 + l15][quad * 8];
            bf16x8 kf1 = *(const bf16x8*)&kbuf[cur][ts * 16 + l15][32 + quad * 8];
            accs[ts] = __builtin_amdgcn_mfma_f32_16x16x32_bf16(qf0, kf0, accs[ts], 0, 0, 0);
            accs[ts] = __builtin_amdgcn_mfma_f32_16x16x32_bf16(qf1, kf1, accs[ts], 0, 0, 0);
        }
        __builtin_amdgcn_s_setprio(0);
        // ---- causal mask: only when unit overlaps/exceeds wave's rows ----
        const int s0 = u * 64;
        const int rowb = q0 + wave * 16 + quad * 4;
        if (s0 + 63 > q0 + wave * 16) {        // wave-uniform
#pragma unroll
            for (int ts = 0; ts < 4; ++ts) {
                int col = s0 + ts * 16 + l15;
#pragma unroll
                for (int r = 0; r < 4; ++r)
                    accs[ts][r] = (col > rowb + r) ? -128.f : accs[ts][r];
            }
        }
        // ---- P = exp2(S); per-lane l; P -> wave-private LDS (C->A) ----
#pragma unroll
        for (int ts = 0; ts < 4; ++ts) {
#pragma unroll
            for (int r = 0; r < 4; ++r) {
                float p = exp2f(accs[ts][r]);
                lsum[r] += p;
                p_lds[wave][quad * 4 + r][ts * 16 + l15] = (bf16_t)p;
            }
        }
        // ---- O += P V ----
        __builtin_amdgcn_s_setprio(1);
#pragma unroll
        for (int kk = 0; kk < 64; kk += 32) {
            bf16x8 pf = *(const bf16x8*)&p_lds[wave][l15][kk + quad * 8];
#pragma unroll
            for (int t2 = 0; t2 < 4; ++t2) {
                bf16x8 vf = *(const bf16x8*)&vbuf[cur][t2 * 16 + l15][kk + quad * 8];
                acc_o[t2] = __builtin_amdgcn_mfma_f32_16x16x32_bf16(pf, vf, acc_o[t2], 0, 0, 0);
            }
        }
        __builtin_amdgcn_s_setprio(0);
        // ---- stage next unit into the buffer everyone is done reading ----
        if (i + 1 < cnt) {
            *(uint4*)&kbuf[cur ^ 1][srow][sc8 * 8] = kr;
            *(uint4*)&vbuf[cur ^ 1][srow][sc8 * 8] = vr;
        }
        u = un;
        cur ^= 1;
    }
#undef LOAD_UNIT

    // ---- one deferred cross-lane l reduction ----
#pragma unroll
    for (int r = 0; r < 4; ++r) {
        float v = lsum[r];
        v += __shfl_xor(v, 1);
        v += __shfl_xor(v, 2);
        v += __shfl_xor(v, 4);
        v += __shfl_xor(v, 8);
        lsum[r] = v;
    }
    // ---- coalesced partials: [slot][tid][16] bf16, register order ----
    const int slot = (b * NTILE + t) * NSMX + s;
    bf16x8 o0, o1;
#pragma unroll
    for (int e = 0; e < 8; ++e) { o0[e] = (bf16_t)acc_o[e >> 2][e & 3]; o1[e] = (bf16_t)acc_o[2 + (e >> 2)][e & 3]; }
    bf16_t* op = Opart + (size_t)slot * 8192 + (size_t)tid * 16;
    *(bf16x8*)op = o0;
    *(bf16x8*)(op + 8) = o1;
    if (l15 == 0) {
#pragma unroll
        for (int r = 0; r < 4; ++r)
            lpart[(size_t)slot * 128 + wave * 16 + quad * 4 + r] = lsum[r];
    }
}

// ---------------------------------------------------------------------------
// Kernel 3: combine partials + normalize. v2: grid (64, B) x 256 thr —
// each tile split across TWO blocks (rows 0-63 / 64-127 via tid offset)
// so 256 blocks cover all 256 CUs (was 128 blocks = half the machine idle
// on a memory-bound pass). Per-thread work/indexing identical: effective
// tid = (bx&1)*256 + threadIdx.x reproduces the attn lane structure.
// ---------------------------------------------------------------------------
__launch_bounds__(256)
__global__ void combine_kernel(const bf16_t* __restrict__ Opart, const float* __restrict__ lpart,
                               float* __restrict__ out) {
    const int t = blockIdx.x >> 1;
    const int b = blockIdx.y;
    const int ns = (t >> 2) + 1;
    const int tid  = (blockIdx.x & 1) * 256 + threadIdx.x;   // 0..511
    const int wave = tid >> 6;
    const int lane = tid & 63;
    const int l15  = lane & 15;
    const int quad = lane >> 4;

    float o[16];
#pragma unroll
    for (int i = 0; i < 16; ++i) o[i] = 0.f;
    float L[4] = {0.f, 0.f, 0.f, 0.f};

    for (int s = 0; s < ns; ++s) {
        const int slot = (b * NTILE + t) * NSMX + s;
        const bf16_t* op = Opart + (size_t)slot * 8192 + (size_t)tid * 16;
        bf16x8 v0 = *(const bf16x8*)op;
        bf16x8 v1 = *(const bf16x8*)(op + 8);
#pragma unroll
        for (int i = 0; i < 8; ++i) { o[i] += (float)v0[i]; o[8 + i] += (float)v1[i]; }
#pragma unroll
        for (int r = 0; r < 4; ++r)
            L[r] += lpart[(size_t)slot * 128 + wave * 16 + quad * 4 + r];
    }
    float inv[4];
#pragma unroll
    for (int r = 0; r < 4; ++r) inv[r] = 1.f / L[r];
    // o[e] with e = t2*4+r -> row = t*128+wave*16+quad*4+r, col = t2*16+l15
#pragma unroll
    for (int t2 = 0; t2 < 4; ++t2) {
#pragma unroll
        for (int r = 0; r < 4; ++r) {
            size_t row = (size_t)b * Tn + t * 128 + wave * 16 + quad * 4 + r;
            out[row * Hn + t2 * 16 + l15] = o[t2 * 4 + r] * inv[r];
        }
    }
}

// ---------------------------------------------------------------------------
extern "C" void kernel_launch(void* const* d_in, const int* in_sizes, int n_in,
                              void* d_out, int out_size, void* d_ws, size_t ws_size,
                              hipStream_t stream) {
    const float* x  = (const float*)d_in[0];
    const float* Wq = (const float*)d_in[1];
    const float* Wk = (const float*)d_in[2];
    const float* Wv = (const float*)d_in[3];
    float* out = (float*)d_out;

    bf16_t* wsb = (bf16_t*)d_ws;
    bf16_t* WT = wsb + WT_OFF;
    bf16_t* qb = wsb + Q_OFF;
    bf16_t* kb = wsb + K_OFF;
    bf16_t* vt = wsb + VT_OFF;
    bf16_t* Opart = wsb + PART_OFF;
    float*  lpart = (float*)(Opart + (size_t)SLOTS * 8192);

    // blocks/batch = sum_t (t/4+1) = 144
    const int per_batch = 144;

    wt_kernel<<<dim3(192 * 1024 / 256), dim3(256), 0, stream>>>(Wq, Wk, Wv, WT);
    proj_kernel<<<dim3(512), dim3(256), 0, stream>>>(x, WT, qb, kb, vt);
    attn_part<<<dim3(per_batch * Bn), dim3(512), 0, stream>>>(qb, kb, vt, Opart, lpart);
    combine_kernel<<<dim3(NTILE * 2, Bn), dim3(256), 0, stream>>>(Opart, lpart, out);
}

// Round 12
// 143.185 us; speedup vs baseline: 1.0307x; 1.0137x over previous
//
#include <hip/hip_runtime.h>
#include <hip/hip_bf16.h>
#include <math.h>

// Problem constants: B=4, T=4096, C=1024, H=64
#define Bn 4
#define Tn 4096
#define Cn 1024
#define Hn 64

typedef __bf16 bf16_t;
typedef __bf16 bf16x8 __attribute__((ext_vector_type(8)));
typedef __bf16 bf16x4 __attribute__((ext_vector_type(4)));
typedef float f32x4 __attribute__((ext_vector_type(4)));

// bf16-element workspace offsets
#define WT_OFF 0
#define Q_OFF   196608
#define K_OFF   (Q_OFF + 1048576)
#define VT_OFF  (K_OFF + 1048576)
#define PART_OFF (VT_OFF + 1048576)     // 3,342,336: Opart bf16 region
// attn tiling: 128-row Q-tiles (32/batch), 64-col units, <=8 splits/tile
#define NTILE 32
#define NSMX 8
#define SLOTS (Bn * NTILE * NSMX)       // 1024 slots x 8192 el (16 KB bf16)

// ---------------------------------------------------------------------------
// FINAL CONFIGURATION — exact revert to the best measured kernel (144.17 us,
// round 8 bench). Session ledger:
//   wins:  dense 512B x-segments (+10 us), 2 blocks/CU co-residency (+6),
//          attn K/V double-buffer single-barrier (+9)
//   nulls: waves/SIMD x2, K-rotation, LDS-capacity-3 @99KB, attn-style
//          pipeline, async-DMA delta, setprio, occupancy-3 (regr), BK=256
//          (regr), combine-split (regr)
// Remaining wall: 84 us harness fills AT the HBM roofline (80-82% peak);
// proj/attn sit at the structural 2-barrier-phase gap that HIP-level
// scheduling cannot close (guide m131-m141).
// ---------------------------------------------------------------------------

// ---------------------------------------------------------------------------
// Kernel 0: WT[n][k] = W_sel[k][n&63] bf16 (scale*log2e folded into Wq rows).
// ---------------------------------------------------------------------------
__global__ void wt_kernel(const float* __restrict__ Wq, const float* __restrict__ Wk,
                          const float* __restrict__ Wv, bf16_t* __restrict__ WT) {
    int idx = blockIdx.x * 256 + threadIdx.x;   // idx = n*1024 + k
    int n = idx >> 10;
    int k = idx & 1023;
    const float* W = (n < 64) ? Wq : (n < 128) ? Wk : Wv;
    float s = (n < 64) ? 0.1803368801111204f : 1.0f;   // H^-0.5 * log2(e)
    WT[idx] = (bf16_t)(W[(size_t)k * 64 + (n & 63)] * s);
}

// ---------------------------------------------------------------------------
// Kernel 1: QKV projection. BN=96, BK=128, grid 512 = 256 M-groups x 2
// N-tiles (pair blk/blk+8 shares the x slice on one XCD). 40 KB LDS.
// W staged via async global_load_lds (linear LDS dest; swizzle carried in
// the per-lane GLOBAL source chunk, rule #21); x staged reg+cvt with dense
// 512 B segments issued before the barrier.
// ---------------------------------------------------------------------------
__launch_bounds__(256, 3)
__global__ void proj_kernel(const float* __restrict__ x, const bf16_t* __restrict__ WT,
                            bf16_t* __restrict__ q, bf16_t* __restrict__ kmat,
                            bf16_t* __restrict__ vt) {
    __shared__ bf16_t xtile[64][128];    // swizzled: chunk c at c^((row&3)<<2)
    __shared__ bf16_t wtile[96][128];    // LINEAR; swizzle in global src chunk

    const int tid  = threadIdx.x;
    const int wave = tid >> 6;
    const int lane = tid & 63;
    const int l15  = lane & 15;
    const int quad = lane >> 4;
    const int blk  = blockIdx.x;
    const int mg = ((blk >> 4) << 3) | (blk & 7);   // 0..255; blk,blk+8 same mg+XCD
    const int j2 = (blk >> 3) & 1;                  // N-tile 0..1
    const int n0 = j2 * 96;

    const int mrow = mg * 64;
    const int srow = tid >> 5;           // 0..7 (32-lane half -> dense 512B segment)
    const int sc   = tid & 31;           // float4 index within 512 B row chunk

    const int wrow_l = (lane >> 4);                          // 0..3
    const int wchunk = (lane & 15) ^ (wrow_l << 2);          // swizzled src chunk

    f32x4 acc[3][2];
#pragma unroll
    for (int nn = 0; nn < 3; ++nn)
#pragma unroll
        for (int rt = 0; rt < 2; ++rt)
            acc[nn][rt] = (f32x4){0.f, 0.f, 0.f, 0.f};

    const int rbase = (wave >> 1) * 32;  // A rows for this wave
    const int cbase = (wave & 1) * 48;   // B cols for this wave

    for (int kt = 0; kt < 8; ++kt) {
        const int k0 = kt * 128;
        // ---- x prefetch to regs: 8 independent dense float4 ----
        float4 xr[8];
        const float* xg = x + (size_t)(mrow + srow) * Cn + k0 + sc * 4;
#pragma unroll
        for (int rr = 0; rr < 8; ++rr)
            xr[rr] = *(const float4*)(xg + (size_t)rr * 8 * Cn);

        if (kt) __syncthreads();         // previous tile fully consumed

        // ---- W: async DMA global->LDS (6 x global_load_lds dwordx4) ----
#pragma unroll
        for (int i = 0; i < 6; ++i) {
            const int row = wave * 24 + i * 4 + wrow_l;
            const bf16_t* src = WT + (size_t)(n0 + row) * Cn + k0 + wchunk * 8;
            __builtin_amdgcn_global_load_lds(
                (const __attribute__((address_space(1))) void*)src,
                (__attribute__((address_space(3))) void*)&wtile[wave * 24 + i * 4][0],
                16, 0, 0);
        }

        // ---- x: cvt + swizzled LDS write ----
#pragma unroll
        for (int rr = 0; rr < 8; ++rr) {
            float4 v = xr[rr];
            bf16x4 c;
            c[0] = (bf16_t)v.x; c[1] = (bf16_t)v.y; c[2] = (bf16_t)v.z; c[3] = (bf16_t)v.w;
            int el = (((sc >> 1) ^ ((srow & 3) << 2)) << 3) + (sc & 1) * 4;
            *(bf16x4*)&xtile[srow + rr * 8][el] = c;
        }
        __syncthreads();                 // drains vmcnt (incl. DMA) + lgkm

        // ---- compute: 4 k-steps of 32 ----
#pragma unroll
        for (int ks = 0; ks < 4; ++ks) {
            const int u = (((ks << 2) | quad) ^ ((l15 & 3) << 2)) << 3;
            bf16x8 af[2];
#pragma unroll
            for (int rt = 0; rt < 2; ++rt)
                af[rt] = *(const bf16x8*)&xtile[rbase + rt * 16 + l15][u];
#pragma unroll
            for (int nn = 0; nn < 3; ++nn) {
                bf16x8 b = *(const bf16x8*)&wtile[cbase + nn * 16 + l15][u];
#pragma unroll
                for (int rt = 0; rt < 2; ++rt)
                    acc[nn][rt] = __builtin_amdgcn_mfma_f32_16x16x32_bf16(af[rt], b, acc[nn][rt], 0, 0, 0);
            }
        }
    }

    // ---- epilogue: C/D layout col=lane&15, row=quad*4+reg ----
#pragma unroll
    for (int nn = 0; nn < 3; ++nn) {
        int n = n0 + cbase + nn * 16 + l15;
#pragma unroll
        for (int rt = 0; rt < 2; ++rt) {
#pragma unroll
            for (int r = 0; r < 4; ++r) {
                int row = mrow + rbase + rt * 16 + quad * 4 + r;
                float v = acc[nn][rt][r];
                if (n < 64) {
                    q[(size_t)row * Hn + n] = (bf16_t)v;
                } else if (n < 128) {
                    kmat[(size_t)row * Hn + (n - 64)] = (bf16_t)v;
                } else {
                    int b  = row >> 12;
                    int tr = row & (Tn - 1);
                    vt[((size_t)b * Hn + (n - 128)) * Tn + tr] = (bf16_t)v;
                }
            }
        }
    }
}

// ---------------------------------------------------------------------------
// Kernel 2: split-KV causal flash attention, 512 thr (8 waves), 128-row
// Q-tile per block: K/V double-buffered staging (2x18 KB) feeds 8 waves,
// ONE barrier per 64-key unit. Tile t has 2t+2 units, ns=ceil(units/8)
// splits round-robin -> 576 blocks. 54 KB LDS. Coalesced bf16 partials.
// s_setprio around MFMA clusters (measured ~null here; kept, harmless).
// ---------------------------------------------------------------------------
__launch_bounds__(512, 4)
__global__ void attn_part(const bf16_t* __restrict__ q, const bf16_t* __restrict__ kmat,
                          const bf16_t* __restrict__ vt, bf16_t* __restrict__ Opart,
                          float* __restrict__ lpart) {
    __shared__ bf16_t kbuf[2][64][72];
    __shared__ bf16_t vbuf[2][64][72];
    __shared__ bf16_t p_lds[8][16][72];

    const int tid  = threadIdx.x;
    const int wave = tid >> 6;
    const int lane = tid & 63;
    const int l15  = lane & 15;
    const int quad = lane >> 4;

    // ---- decode (b, tile t, split s): cum(g) = 2g(g+1), 4 tiles/group ----
    const int blk = blockIdx.x;
    const int b   = blk & 3;
    const int w   = blk >> 2;           // 0..143
    int g = (int)((sqrtf(1.0f + 2.0f * (float)w) - 1.0f) * 0.5f);
    while (2 * (g + 1) * (g + 2) <= w) ++g;
    while (2 * g * (g + 1) > w) --g;
    const int rem = w - 2 * g * (g + 1);    // 0 .. 4(g+1)-1
    const int ns  = g + 1;
    const int t   = 4 * g + rem / ns;       // q-tile 0..31 (128 rows)
    const int s   = rem - (rem / ns) * ns;  // split 0..ns-1
    const int n_u = 2 * t + 2;              // KV units for this tile
    const int cnt = (n_u - 1 - s) / ns + 1; // units for this split
    const int q0  = t * 128;

    size_t qbase = ((size_t)b * Tn + q0 + wave * 16 + l15) * Hn;
    bf16x8 qf0 = *(const bf16x8*)(q + qbase + quad * 8);
    bf16x8 qf1 = *(const bf16x8*)(q + qbase + 32 + quad * 8);

    const bf16_t* kb = kmat + (size_t)b * Tn * Hn;
    const bf16_t* vb = vt + (size_t)b * Hn * Tn;

    f32x4 acc_o[4];
#pragma unroll
    for (int i = 0; i < 4; ++i) acc_o[i] = (f32x4){0.f, 0.f, 0.f, 0.f};
    float lsum[4] = {0.f, 0.f, 0.f, 0.f};

    const int srow = tid >> 3;   // staging: 64 rows x 8 chunks over 512 thr
    const int sc8  = tid & 7;

    uint4 kr, vr;
#define LOAD_UNIT(uu)                                                           \
    {                                                                           \
        const int s0l = (uu) * 64;                                              \
        kr = *(const uint4*)(kb + (size_t)(s0l + srow) * Hn + sc8 * 8);         \
        vr = *(const uint4*)(vb + (size_t)srow * Tn + s0l + sc8 * 8);           \
    }

    LOAD_UNIT(s);
    int u = s;
    int cur = 0;
    *(uint4*)&kbuf[0][srow][sc8 * 8] = kr;
    *(uint4*)&vbuf[0][srow][sc8 * 8] = vr;

    for (int i = 0; i < cnt; ++i) {
        __syncthreads();                    // buf[cur] visible; buf[cur^1] free
        const int un = u + ns;
        if (i + 1 < cnt) LOAD_UNIT(un);     // in flight across compute

        // ---- S = Q K^T (scale pre-folded into q) ----
        f32x4 accs[4];
#pragma unroll
        for (int ts = 0; ts < 4; ++ts) accs[ts] = (f32x4){0.f, 0.f, 0.f, 0.f};
        __builtin_amdgcn_s_setprio(1);
#pragma unroll
        for (int ts = 0; ts < 4; ++ts) {
            bf16x8 kf0 = *(const bf16x8*)&kbuf[cur][ts * 16 + l15][quad * 8];
            bf16x8 kf1 = *(const bf16x8*)&kbuf[cur][ts * 16 + l15][32 + quad * 8];
            accs[ts] = __builtin_amdgcn_mfma_f32_16x16x32_bf16(qf0, kf0, accs[ts], 0, 0, 0);
            accs[ts] = __builtin_amdgcn_mfma_f32_16x16x32_bf16(qf1, kf1, accs[ts], 0, 0, 0);
        }
        __builtin_amdgcn_s_setprio(0);
        // ---- causal mask: only when unit overlaps/exceeds wave's rows ----
        const int s0 = u * 64;
        const int rowb = q0 + wave * 16 + quad * 4;
        if (s0 + 63 > q0 + wave * 16) {        // wave-uniform
#pragma unroll
            for (int ts = 0; ts < 4; ++ts) {
                int col = s0 + ts * 16 + l15;
#pragma unroll
                for (int r = 0; r < 4; ++r)
                    accs[ts][r] = (col > rowb + r) ? -128.f : accs[ts][r];
            }
        }
        // ---- P = exp2(S); per-lane l; P -> wave-private LDS (C->A) ----
#pragma unroll
        for (int ts = 0; ts < 4; ++ts) {
#pragma unroll
            for (int r = 0; r < 4; ++r) {
                float p = exp2f(accs[ts][r]);
                lsum[r] += p;
                p_lds[wave][quad * 4 + r][ts * 16 + l15] = (bf16_t)p;
            }
        }
        // ---- O += P V ----
        __builtin_amdgcn_s_setprio(1);
#pragma unroll
        for (int kk = 0; kk < 64; kk += 32) {
            bf16x8 pf = *(const bf16x8*)&p_lds[wave][l15][kk + quad * 8];
#pragma unroll
            for (int t2 = 0; t2 < 4; ++t2) {
                bf16x8 vf = *(const bf16x8*)&vbuf[cur][t2 * 16 + l15][kk + quad * 8];
                acc_o[t2] = __builtin_amdgcn_mfma_f32_16x16x32_bf16(pf, vf, acc_o[t2], 0, 0, 0);
            }
        }
        __builtin_amdgcn_s_setprio(0);
        // ---- stage next unit into the buffer everyone is done reading ----
        if (i + 1 < cnt) {
            *(uint4*)&kbuf[cur ^ 1][srow][sc8 * 8] = kr;
            *(uint4*)&vbuf[cur ^ 1][srow][sc8 * 8] = vr;
        }
        u = un;
        cur ^= 1;
    }
#undef LOAD_UNIT

    // ---- one deferred cross-lane l reduction ----
#pragma unroll
    for (int r = 0; r < 4; ++r) {
        float v = lsum[r];
        v += __shfl_xor(v, 1);
        v += __shfl_xor(v, 2);
        v += __shfl_xor(v, 4);
        v += __shfl_xor(v, 8);
        lsum[r] = v;
    }
    // ---- coalesced partials: [slot][tid][16] bf16, register order ----
    const int slot = (b * NTILE + t) * NSMX + s;
    bf16x8 o0, o1;
#pragma unroll
    for (int e = 0; e < 8; ++e) { o0[e] = (bf16_t)acc_o[e >> 2][e & 3]; o1[e] = (bf16_t)acc_o[2 + (e >> 2)][e & 3]; }
    bf16_t* op = Opart + (size_t)slot * 8192 + (size_t)tid * 16;
    *(bf16x8*)op = o0;
    *(bf16x8*)(op + 8) = o1;
    if (l15 == 0) {
#pragma unroll
        for (int r = 0; r < 4; ++r)
            lpart[(size_t)slot * 128 + wave * 16 + quad * 4 + r] = lsum[r];
    }
}

// ---------------------------------------------------------------------------
// Kernel 3: combine partials + normalize. Grid (32, B), 512 thr mirroring
// attn lane structure: thread sums its own 16 contiguous elements per slot.
// ---------------------------------------------------------------------------
__launch_bounds__(512)
__global__ void combine_kernel(const bf16_t* __restrict__ Opart, const float* __restrict__ lpart,
                               float* __restrict__ out) {
    const int t = blockIdx.x;
    const int b = blockIdx.y;
    const int ns = (t >> 2) + 1;
    const int tid  = threadIdx.x;
    const int wave = tid >> 6;
    const int lane = tid & 63;
    const int l15  = lane & 15;
    const int quad = lane >> 4;

    float o[16];
#pragma unroll
    for (int i = 0; i < 16; ++i) o[i] = 0.f;
    float L[4] = {0.f, 0.f, 0.f, 0.f};

    for (int s = 0; s < ns; ++s) {
        const int slot = (b * NTILE + t) * NSMX + s;
        const bf16_t* op = Opart + (size_t)slot * 8192 + (size_t)tid * 16;
        bf16x8 v0 = *(const bf16x8*)op;
        bf16x8 v1 = *(const bf16x8*)(op + 8);
#pragma unroll
        for (int i = 0; i < 8; ++i) { o[i] += (float)v0[i]; o[8 + i] += (float)v1[i]; }
#pragma unroll
        for (int r = 0; r < 4; ++r)
            L[r] += lpart[(size_t)slot * 128 + wave * 16 + quad * 4 + r];
    }
    float inv[4];
#pragma unroll
    for (int r = 0; r < 4; ++r) inv[r] = 1.f / L[r];
    // o[e] with e = t2*4+r -> row = t*128+wave*16+quad*4+r, col = t2*16+l15
#pragma unroll
    for (int t2 = 0; t2 < 4; ++t2) {
#pragma unroll
        for (int r = 0; r < 4; ++r) {
            size_t row = (size_t)b * Tn + t * 128 + wave * 16 + quad * 4 + r;
            out[row * Hn + t2 * 16 + l15] = o[t2 * 4 + r] * inv[r];
        }
    }
}

// ---------------------------------------------------------------------------
extern "C" void kernel_launch(void* const* d_in, const int* in_sizes, int n_in,
                              void* d_out, int out_size, void* d_ws, size_t ws_size,
                              hipStream_t stream) {
    const float* x  = (const float*)d_in[0];
    const float* Wq = (const float*)d_in[1];
    const float* Wk = (const float*)d_in[2];
    const float* Wv = (const float*)d_in[3];
    float* out = (float*)d_out;

    bf16_t* wsb = (bf16_t*)d_ws;
    bf16_t* WT = wsb + WT_OFF;
    bf16_t* qb = wsb + Q_OFF;
    bf16_t* kb = wsb + K_OFF;
    bf16_t* vt = wsb + VT_OFF;
    bf16_t* Opart = wsb + PART_OFF;
    float*  lpart = (float*)(Opart + (size_t)SLOTS * 8192);

    // blocks/batch = sum_t (t/4+1) = 144
    const int per_batch = 144;

    wt_kernel<<<dim3(192 * 1024 / 256), dim3(256), 0, stream>>>(Wq, Wk, Wv, WT);
    proj_kernel<<<dim3(512), dim3(256), 0, stream>>>(x, WT, qb, kb, vt);
    attn_part<<<dim3(per_batch * Bn), dim3(512), 0, stream>>>(qb, kb, vt, Opart, lpart);
    combine_kernel<<<dim3(NTILE, Bn), dim3(512), 0, stream>>>(Opart, lpart, out);
}